// Round 18
// baseline (49.250 us; speedup 1.0000x reference)
//
#include <hip/hip_runtime.h>
#include <math.h>

#define L_IN   1048576
#define NBATCH 16
#define T_FR   2049
#define NBINS  513

// ---------------- complex helpers (scalar — R14 proved packed f2 regresses) ----------------
struct C2 { float r, i; };
__device__ __forceinline__ C2 cadd(C2 a, C2 b){ return {a.r+b.r, a.i+b.i}; }
__device__ __forceinline__ C2 csub(C2 a, C2 b){ return {a.r-b.r, a.i-b.i}; }
__device__ __forceinline__ C2 cmul(C2 a, C2 b){ return {a.r*b.r - a.i*b.i, a.r*b.i + a.i*b.r}; }
__device__ __forceinline__ C2 cnegi(C2 a){ return {a.i, -a.r}; }            // a * (-i)
#define RSQ2 0.70710678118654752f
__device__ __forceinline__ C2 cw8 (C2 a){ return { RSQ2*(a.r+a.i),  RSQ2*(a.i-a.r)}; }  // a * w8
__device__ __forceinline__ C2 cw83(C2 a){ return { RSQ2*(a.i-a.r), -RSQ2*(a.r+a.i)}; }  // a * w8^3

#if __has_builtin(__builtin_amdgcn_sqrtf)
#define FSQRT(x) __builtin_amdgcn_sqrtf(x)     // raw v_sqrt_f32 (1 instr, ~1 ulp)
#else
#define FSQRT(x) sqrtf(x)
#endif

// 8-point DFT, natural order in/out, w8 = e^{-i pi/4}. (verified: impulse at x1 -> y_k = w8^k)
__device__ __forceinline__ void dft8(const C2 x[8], C2 y[8]) {
  C2 ea0 = cadd(x[0], x[4]), ea1 = csub(x[0], x[4]);
  C2 eb0 = cadd(x[2], x[6]), eb1 = csub(x[2], x[6]);
  C2 oa0 = cadd(x[1], x[5]), oa1 = csub(x[1], x[5]);
  C2 ob0 = cadd(x[3], x[7]), ob1 = csub(x[3], x[7]);
  C2 E0 = cadd(ea0, eb0), E2 = csub(ea0, eb0);
  C2 nb = cnegi(eb1);
  C2 E1 = cadd(ea1, nb),  E3 = csub(ea1, nb);
  C2 O0 = cadd(oa0, ob0), O2 = csub(oa0, ob0);
  C2 no = cnegi(ob1);
  C2 O1 = cadd(oa1, no),  O3 = csub(oa1, no);
  y[0] = cadd(E0, O0);  y[4] = csub(E0, O0);
  C2 t1 = cw8(O1);      y[1] = cadd(E1, t1); y[5] = csub(E1, t1);
  C2 t2 = cnegi(O2);    y[2] = cadd(E2, t2); y[6] = csub(E2, t2);
  C2 t3 = cw83(O3);     y[3] = cadd(E3, t3); y[7] = csub(E3, t3);
}

// LDS bank-spread swizzle (bijective on [0,512)) — verified per access pattern in R8.
__device__ __forceinline__ int phys(int idx) { return idx ^ ((idx >> 4) & 15); }

__device__ __forceinline__ unsigned short f2bf(float f) {
  unsigned int u = __builtin_bit_cast(unsigned int, f);
  u += 0x7FFFu + ((u >> 16) & 1u);   // RNE
  return (unsigned short)(u >> 16);
}

#define TWOPI 6.283185307179586f

// raw (unwindowed) frame load; reflect only for edge frames (wave-uniform branch)
__device__ __forceinline__ void load_raw(float2 v[8], const float* __restrict__ xb,
                                         int tt, int t) {
  const int s0 = tt*512 - 512;
  if (tt != 0 && tt != 2048) {
    #pragma unroll
    for (int j = 0; j < 8; ++j) v[j] = *(const float2*)&xb[s0 + 2*(t + 64*j)];
  } else {
    #pragma unroll
    for (int j = 0; j < 8; ++j) {
      int e0 = s0 + 2*(t + 64*j), e1 = e0 + 1;
      int r0 = e0 < 0 ? -e0 : (e0 >= L_IN ? 2*L_IN - 2 - e0 : e0);
      int r1 = e1 < 0 ? -e1 : (e1 >= L_IN ? 2*L_IN - 2 - e1 : e1);
      v[j] = { xb[r0], xb[r1] };
    }
  }
}

// per-frame: (0.5-scaled) window -> radix-8 x3 Stockham (2 LDS exchanges) ->
// shfl real unpack with pre-folded vu = -i*W_1024^k -> bf16 magnitude stage.
// FENCE-FREE (the single change vs R17): per-wave DS ops are serviced in order —
// stage-N+1 reads (issued after stage-N writes) return new data; stage-2 reads
// (issued before the NEXT frame's stage-0 writes) return old data, which is
// correct. Same-array may-aliasing pins compiler DS order; its counted
// lgkmcnt(N) auto-waits cover register deps without full drains.
// Hazard model validated on HW by R13 (passed, absmax 0.25).
__device__ __forceinline__ void process_frame(const float2 v[8], const float2 wl[8],
    const C2 tws1[8], const C2 tws2[8], const C2 vu[8],
    C2* __restrict__ cfw, unsigned short (* __restrict__ mag)[18], int t, int tl)
{
  C2 x[8], y[8];
  #pragma unroll
  for (int j = 0; j < 8; ++j) x[j] = { v[j].x * wl[j].x, v[j].y * wl[j].y };
  dft8(x, y);                                   // stage 0 (Ls=1)
  #pragma unroll
  for (int k = 0; k < 8; ++k) cfw[phys(8*t + k)] = y[k];
  {                                             // stage 1 (Ls=8): tw = W_64^{m j}
    const int m = t & 7, g = t >> 3;
    C2 xs[8];
    #pragma unroll
    for (int j = 0; j < 8; ++j) xs[j] = cfw[phys(t + 64*j)];
    #pragma unroll
    for (int j = 1; j < 8; ++j) xs[j] = cmul(xs[j], tws1[j]);
    dft8(xs, y);
    #pragma unroll
    for (int k = 0; k < 8; ++k) cfw[phys(g*64 + m + 8*k)] = y[k];
  }
  C2 z[8];
  {                                             // stage 2 (Ls=64): tw = W_512^{t j}
    C2 xs[8];
    #pragma unroll
    for (int j = 0; j < 8; ++j) xs[j] = cfw[phys(t + 64*j)];
    #pragma unroll
    for (int j = 1; j < 8; ++j) xs[j] = cmul(xs[j], tws2[j]);
    dft8(xs, z);                                // z[k] = Z[t + 64k], natural order, regs only
  }
  // real-FFT unpack via cross-lane shuffle: partner Z[(512-k)&511]
  // k=t+64j: t>=1 -> lane 64-t, reg 7-j; t==0 -> lane 0 (self), reg (8-j)&7
  const int pl = (64 - t) & 63;
  #pragma unroll
  for (int j = 0; j < 8; ++j) {
    const int k = t + 64*j;
    C2 Zp = { __shfl(z[7-j].r, pl), __shfl(z[7-j].i, pl) };
    if (t == 0) Zp = z[(8-j) & 7];
    C2 Zk = z[j];
    C2 V  = vu[j];                              // -i * W_1024^k
    float Are = Zk.r + Zp.r, Aim = Zk.i - Zp.i;
    float Bre = Zk.r - Zp.r, Bim = Zk.i + Zp.i;
    float Xr = Are + (V.r*Bre - V.i*Bim);
    float Xi = Aim + (V.r*Bim + V.i*Bre);
    mag[k][tl] = f2bf(FSQRT(Xr*Xr + Xi*Xi));
  }
  if (t == 0) mag[512][tl] = f2bf(2.0f * fabsf(z[0].r - z[0].i));  // X[512], 0.5-window fix
}

// One block = 16 consecutive frames of one batch; 4 waves x 4 frames — the
// proven 49.2us R17 structure, FENCEs removed (isolated A/B).
__global__ __launch_bounds__(256, 3)
void stft_fft(const float* __restrict__ input,
              const float* __restrict__ basis,
              float* __restrict__ out)
{
  __shared__ C2 cf[4][512];                 // per-wave exchange array (16 KB)
  __shared__ unsigned short mag[513][18];   // bf16 transpose staging (18.0 KB) -> 34.5 KB

  const int tid = threadIdx.x;
  const int t   = tid & 63;        // lane
  const int w   = tid >> 6;        // wave 0..3
  const int b   = blockIdx.y;      // batch
  const int t0  = blockIdx.x << 4; // first frame of this block

  // ---- per-lane twiddles: 3 sincos + complex power chains ----
  // tws1[j] = (W_64^m)^j,  tws2[j] = (W_512^t)^j,
  // vu[j]   = -i*W_1024^(t+64j) = W_1024^t * D[j],  D[j] = -i*W_16^j (constants)
  C2 tws1[8], tws2[8], vu[8];
  {
    const float SN[8] = {0.f, 0.3826834324f, 0.7071067812f, 0.9238795325f,
                         1.f, 0.9238795325f, 0.7071067812f, 0.3826834324f};
    const float CS[8] = {1.f, 0.9238795325f, 0.7071067812f, 0.3826834324f,
                         0.f,-0.3826834324f,-0.7071067812f,-0.9238795325f};
    float s, c;
    __sincosf((TWOPI/64.0f)   * (float)(t & 7), &s, &c); C2 W1 = { c, -s };
    __sincosf((TWOPI/512.0f)  * (float)t,       &s, &c); C2 W2 = { c, -s };
    __sincosf((TWOPI/1024.0f) * (float)t,       &s, &c); C2 Wt = { c, -s };
    tws1[1] = W1;  tws2[1] = W2;
    #pragma unroll
    for (int j = 2; j < 8; ++j) {
      tws1[j] = cmul(tws1[j-1], W1);
      tws2[j] = cmul(tws2[j-1], W2);
    }
    #pragma unroll
    for (int j = 0; j < 8; ++j) {
      C2 D = { -SN[j], -CS[j] };               // -i * W_16^j
      vu[j] = cmul(Wt, D);
    }
  }

  // ---- window preload, scaled by 0.5 (folds the unpack's 0.5) ----
  float2 wl[8];
  #pragma unroll
  for (int j = 0; j < 8; ++j) {
    float2 wv = *(const float2*)&basis[2*(t + 64*j)];
    wl[j] = { 0.5f * wv.x, 0.5f * wv.y };
  }

  const float* xb = input + (size_t)b * L_IN;
  C2* cfw = cf[w];
  const int base = t0 + w*4;

  // ---- 4 frames per wave, ping-pong prefetch ----
  float2 v0[8], v1[8];
  if (base     <= 2048) load_raw(v0, xb, base,     t);
  if (base + 1 <= 2048) load_raw(v1, xb, base + 1, t);
  if (base     <= 2048) process_frame(v0, wl, tws1, tws2, vu, cfw, mag, t, w*4);
  if (base + 2 <= 2048) load_raw(v0, xb, base + 2, t);
  if (base + 1 <= 2048) process_frame(v1, wl, tws1, tws2, vu, cfw, mag, t, w*4 + 1);
  if (base + 3 <= 2048) load_raw(v1, xb, base + 3, t);
  if (base + 2 <= 2048) process_frame(v0, wl, tws1, tws2, vu, cfw, mag, t, w*4 + 2);
  if (base + 3 <= 2048) process_frame(v1, wl, tws1, tws2, vu, cfw, mag, t, w*4 + 3);

  __syncthreads();

  // ---- coalesced output: 64 B chunks along t, bf16 -> f32 ----
  const size_t ob = (size_t)b * NBINS * T_FR;
  for (int idx = tid; idx < NBINS*16; idx += 256) {
    const int row = idx >> 4, tl = idx & 15, tt = t0 + tl;
    if (tt <= 2048) {
      unsigned int u = (unsigned int)mag[row][tl] << 16;
      out[ob + (size_t)row * T_FR + tt] = __builtin_bit_cast(float, u);
    }
  }
}

extern "C" void kernel_launch(void* const* d_in, const int* in_sizes, int n_in,
                              void* d_out, int out_size, void* d_ws, size_t ws_size,
                              hipStream_t stream) {
  const float* input = (const float*)d_in[0];
  const float* basis = (const float*)d_in[1];
  float* out = (float*)d_out;
  // 129 frame-tiles of 16 (last tile: frame 2048 only) x 16 batches
  stft_fft<<<dim3(129, 16), 256, 0, stream>>>(input, basis, out);
}

// Round 19
// 47.465 us; speedup vs baseline: 1.0376x; 1.0376x over previous
//
#include <hip/hip_runtime.h>
#include <math.h>

#define L_IN   1048576
#define NBATCH 16
#define T_FR   2049
#define NBINS  513

// ---------------- complex helpers (scalar — R14 proved packed f2 regresses) ----------------
struct C2 { float r, i; };
__device__ __forceinline__ C2 cadd(C2 a, C2 b){ return {a.r+b.r, a.i+b.i}; }
__device__ __forceinline__ C2 csub(C2 a, C2 b){ return {a.r-b.r, a.i-b.i}; }
__device__ __forceinline__ C2 cmul(C2 a, C2 b){ return {a.r*b.r - a.i*b.i, a.r*b.i + a.i*b.r}; }
__device__ __forceinline__ C2 cnegi(C2 a){ return {a.i, -a.r}; }            // a * (-i)
#define RSQ2 0.70710678118654752f
__device__ __forceinline__ C2 cw8 (C2 a){ return { RSQ2*(a.r+a.i),  RSQ2*(a.i-a.r)}; }  // a * w8
__device__ __forceinline__ C2 cw83(C2 a){ return { RSQ2*(a.i-a.r), -RSQ2*(a.r+a.i)}; }  // a * w8^3

#if __has_builtin(__builtin_amdgcn_sqrtf)
#define FSQRT(x) __builtin_amdgcn_sqrtf(x)     // raw v_sqrt_f32 (1 instr, ~1 ulp)
#else
#define FSQRT(x) sqrtf(x)
#endif

// 8-point DFT, natural order in/out, w8 = e^{-i pi/4}. (verified: impulse at x1 -> y_k = w8^k)
__device__ __forceinline__ void dft8(const C2 x[8], C2 y[8]) {
  C2 ea0 = cadd(x[0], x[4]), ea1 = csub(x[0], x[4]);
  C2 eb0 = cadd(x[2], x[6]), eb1 = csub(x[2], x[6]);
  C2 oa0 = cadd(x[1], x[5]), oa1 = csub(x[1], x[5]);
  C2 ob0 = cadd(x[3], x[7]), ob1 = csub(x[3], x[7]);
  C2 E0 = cadd(ea0, eb0), E2 = csub(ea0, eb0);
  C2 nb = cnegi(eb1);
  C2 E1 = cadd(ea1, nb),  E3 = csub(ea1, nb);
  C2 O0 = cadd(oa0, ob0), O2 = csub(oa0, ob0);
  C2 no = cnegi(ob1);
  C2 O1 = cadd(oa1, no),  O3 = csub(oa1, no);
  y[0] = cadd(E0, O0);  y[4] = csub(E0, O0);
  C2 t1 = cw8(O1);      y[1] = cadd(E1, t1); y[5] = csub(E1, t1);
  C2 t2 = cnegi(O2);    y[2] = cadd(E2, t2); y[6] = csub(E2, t2);
  C2 t3 = cw83(O3);     y[3] = cadd(E3, t3); y[7] = csub(E3, t3);
}

// LDS bank-spread swizzle (bijective on [0,512)) — verified per access pattern in R8.
__device__ __forceinline__ int phys(int idx) { return idx ^ ((idx >> 4) & 15); }

__device__ __forceinline__ unsigned short f2bf(float f) {
  unsigned int u = __builtin_bit_cast(unsigned int, f);
  u += 0x7FFFu + ((u >> 16) & 1u);   // RNE
  return (unsigned short)(u >> 16);
}

#define TWOPI 6.283185307179586f

// raw (unwindowed) frame load; reflect only for edge frames (wave-uniform branch)
__device__ __forceinline__ void load_raw(float2 v[8], const float* __restrict__ xb,
                                         int tt, int t) {
  const int s0 = tt*512 - 512;
  if (tt != 0 && tt != 2048) {
    #pragma unroll
    for (int j = 0; j < 8; ++j) v[j] = *(const float2*)&xb[s0 + 2*(t + 64*j)];
  } else {
    #pragma unroll
    for (int j = 0; j < 8; ++j) {
      int e0 = s0 + 2*(t + 64*j), e1 = e0 + 1;
      int r0 = e0 < 0 ? -e0 : (e0 >= L_IN ? 2*L_IN - 2 - e0 : e0);
      int r1 = e1 < 0 ? -e1 : (e1 >= L_IN ? 2*L_IN - 2 - e1 : e1);
      v[j] = { xb[r0], xb[r1] };
    }
  }
}

// per-frame: (0.5-scaled) window -> radix-8 x3 Stockham (2 LDS exchanges) ->
// symmetric shfl real unpack -> bf16 magnitude stage.  FENCE-free (R18: neutral
// vs explicit drains — compiler's counted lgkmcnt covers the hazards).
//
// Symmetric unpack (R19): for pair (k, 512-k):  A' = conj(A), B' = -conj(B),
// V' = conj(V)  =>  |X_k| = |A + V*B|,  |X_{512-k}| = |A - V*B|.
// One partner fetch + one V*B yields BOTH bins: j=0..3 only, 8 bpermutes.
// Lane 0: j=0 self-partner gives bins 0 and 512; bin 256 = 2|z[4]|.
__device__ __forceinline__ void process_frame(const float2 v[8], const float2 wl[8],
    const C2 tws1[8], const C2 tws2[8], const C2 vu[4],
    C2* __restrict__ cfw, unsigned short (* __restrict__ mag)[18], int t, int tl)
{
  C2 x[8], y[8];
  #pragma unroll
  for (int j = 0; j < 8; ++j) x[j] = { v[j].x * wl[j].x, v[j].y * wl[j].y };
  dft8(x, y);                                   // stage 0 (Ls=1)
  #pragma unroll
  for (int k = 0; k < 8; ++k) cfw[phys(8*t + k)] = y[k];
  {                                             // stage 1 (Ls=8): tw = W_64^{m j}
    const int m = t & 7, g = t >> 3;
    C2 xs[8];
    #pragma unroll
    for (int j = 0; j < 8; ++j) xs[j] = cfw[phys(t + 64*j)];
    #pragma unroll
    for (int j = 1; j < 8; ++j) xs[j] = cmul(xs[j], tws1[j]);
    dft8(xs, y);
    #pragma unroll
    for (int k = 0; k < 8; ++k) cfw[phys(g*64 + m + 8*k)] = y[k];
  }
  C2 z[8];
  {                                             // stage 2 (Ls=64): tw = W_512^{t j}
    C2 xs[8];
    #pragma unroll
    for (int j = 0; j < 8; ++j) xs[j] = cfw[phys(t + 64*j)];
    #pragma unroll
    for (int j = 1; j < 8; ++j) xs[j] = cmul(xs[j], tws2[j]);
    dft8(xs, z);                                // z[k] = Z[t + 64k], natural order, regs only
  }
  // symmetric real-FFT unpack: partner Z[512-k] for k=t+64j, j=0..3
  // k=t+64j: t>=1 -> lane 64-t, reg 7-j; t==0 -> lane 0 (self), reg (8-j)&7
  const int pl = (64 - t) & 63;
  #pragma unroll
  for (int j = 0; j < 4; ++j) {
    const int k = t + 64*j;
    C2 Zp = { __shfl(z[7-j].r, pl), __shfl(z[7-j].i, pl) };
    if (t == 0) Zp = z[(8-j) & 7];
    C2 Zk = z[j];
    C2 V  = vu[j];                              // -i * W_1024^k
    float Are = Zk.r + Zp.r, Aim = Zk.i - Zp.i;
    float Bre = Zk.r - Zp.r, Bim = Zk.i + Zp.i;
    float VBr = V.r*Bre - V.i*Bim;
    float VBi = V.r*Bim + V.i*Bre;
    float Xr = Are + VBr, Xi = Aim + VBi;       // X_k
    float Yr = Are - VBr, Yi = Aim - VBi;       // conj(X_{512-k}) — same magnitude
    mag[k][tl]       = f2bf(FSQRT(Xr*Xr + Xi*Xi));
    mag[512 - k][tl] = f2bf(FSQRT(Yr*Yr + Yi*Yi));
  }
  if (t == 0) {                                 // self-paired bin 256: |X| = 2|Z[256]|
    C2 z4 = z[4];
    mag[256][tl] = f2bf(2.0f * FSQRT(z4.r*z4.r + z4.i*z4.i));
  }
}

// One block = 16 consecutive frames of one batch; 4 waves x 4 frames — the
// proven 49.2us R17/R18 structure with the symmetric (half-cost) unpack.
__global__ __launch_bounds__(256, 3)
void stft_fft(const float* __restrict__ input,
              const float* __restrict__ basis,
              float* __restrict__ out)
{
  __shared__ C2 cf[4][512];                 // per-wave exchange array (16 KB)
  __shared__ unsigned short mag[513][18];   // bf16 transpose staging (18.0 KB) -> 34.5 KB

  const int tid = threadIdx.x;
  const int t   = tid & 63;        // lane
  const int w   = tid >> 6;        // wave 0..3
  const int b   = blockIdx.y;      // batch
  const int t0  = blockIdx.x << 4; // first frame of this block

  // ---- per-lane twiddles: 3 sincos + complex power chains ----
  // tws1[j] = (W_64^m)^j,  tws2[j] = (W_512^t)^j,
  // vu[j]   = -i*W_1024^(t+64j) = W_1024^t * D[j],  D[j] = -i*W_16^j (j=0..3)
  C2 tws1[8], tws2[8], vu[4];
  {
    const float SN[4] = {0.f, 0.3826834324f, 0.7071067812f, 0.9238795325f};
    const float CS[4] = {1.f, 0.9238795325f, 0.7071067812f, 0.3826834324f};
    float s, c;
    __sincosf((TWOPI/64.0f)   * (float)(t & 7), &s, &c); C2 W1 = { c, -s };
    __sincosf((TWOPI/512.0f)  * (float)t,       &s, &c); C2 W2 = { c, -s };
    __sincosf((TWOPI/1024.0f) * (float)t,       &s, &c); C2 Wt = { c, -s };
    tws1[1] = W1;  tws2[1] = W2;
    #pragma unroll
    for (int j = 2; j < 8; ++j) {
      tws1[j] = cmul(tws1[j-1], W1);
      tws2[j] = cmul(tws2[j-1], W2);
    }
    #pragma unroll
    for (int j = 0; j < 4; ++j) {
      C2 D = { -SN[j], -CS[j] };               // -i * W_16^j
      vu[j] = cmul(Wt, D);
    }
  }

  // ---- window preload, scaled by 0.5 (folds the unpack's 0.5) ----
  float2 wl[8];
  #pragma unroll
  for (int j = 0; j < 8; ++j) {
    float2 wv = *(const float2*)&basis[2*(t + 64*j)];
    wl[j] = { 0.5f * wv.x, 0.5f * wv.y };
  }

  const float* xb = input + (size_t)b * L_IN;
  C2* cfw = cf[w];
  const int base = t0 + w*4;

  // ---- 4 frames per wave, ping-pong prefetch ----
  float2 v0[8], v1[8];
  if (base     <= 2048) load_raw(v0, xb, base,     t);
  if (base + 1 <= 2048) load_raw(v1, xb, base + 1, t);
  if (base     <= 2048) process_frame(v0, wl, tws1, tws2, vu, cfw, mag, t, w*4);
  if (base + 2 <= 2048) load_raw(v0, xb, base + 2, t);
  if (base + 1 <= 2048) process_frame(v1, wl, tws1, tws2, vu, cfw, mag, t, w*4 + 1);
  if (base + 3 <= 2048) load_raw(v1, xb, base + 3, t);
  if (base + 2 <= 2048) process_frame(v0, wl, tws1, tws2, vu, cfw, mag, t, w*4 + 2);
  if (base + 3 <= 2048) process_frame(v1, wl, tws1, tws2, vu, cfw, mag, t, w*4 + 3);

  __syncthreads();

  // ---- coalesced output: 64 B chunks along t, bf16 -> f32 ----
  const size_t ob = (size_t)b * NBINS * T_FR;
  for (int idx = tid; idx < NBINS*16; idx += 256) {
    const int row = idx >> 4, tl = idx & 15, tt = t0 + tl;
    if (tt <= 2048) {
      unsigned int u = (unsigned int)mag[row][tl] << 16;
      out[ob + (size_t)row * T_FR + tt] = __builtin_bit_cast(float, u);
    }
  }
}

extern "C" void kernel_launch(void* const* d_in, const int* in_sizes, int n_in,
                              void* d_out, int out_size, void* d_ws, size_t ws_size,
                              hipStream_t stream) {
  const float* input = (const float*)d_in[0];
  const float* basis = (const float*)d_in[1];
  float* out = (float*)d_out;
  // 129 frame-tiles of 16 (last tile: frame 2048 only) x 16 batches
  stft_fft<<<dim3(129, 16), 256, 0, stream>>>(input, basis, out);
}